// Round 8
// baseline (272.211 us; speedup 1.0000x reference)
//
#include <hip/hip_runtime.h>
#include <climits>

typedef __attribute__((ext_vector_type(8))) short s8;      // 8 bf16 = 4 VGPRs
typedef __attribute__((ext_vector_type(4))) float f32x4;   // MFMA acc

#define BQ    256
#define DDIM  256
#define NBANK 100000
#define BN    64                          // bank cols per tile (4 col-tiles of 16)
#define NJB   ((NBANK + BN - 1) / BN)     // 1563
#define SENT  1e30f

// Split fp32 x into bf16 hi (round-half-up) + bf16 lo: x ~= hi + lo, |err| <~ 2^-18|x|
__device__ inline void splitElem(float x, s8& h, s8& l, int i) {
    unsigned u  = __float_as_uint(x);
    unsigned uh = (u + 0x8000u) & 0xFFFF0000u;
    h[i] = (short)(uh >> 16);
    float lf = x - __uint_as_float(uh);            // exact
    l[i] = (short)((__float_as_uint(lf) + 0x8000u) >> 16);
}

__device__ inline void split8(const float4 v0, const float4 v1, s8& h, s8& l) {
    splitElem(v0.x, h, l, 0); splitElem(v0.y, h, l, 1);
    splitElem(v0.z, h, l, 2); splitElem(v0.w, h, l, 3);
    splitElem(v1.x, h, l, 4); splitElem(v1.y, h, l, 5);
    splitElem(v1.z, h, l, 6); splitElem(v1.w, h, l, 7);
}

__device__ inline float sq8(const float4 v0, const float4 v1, float s) {
    s = fmaf(v0.x, v0.x, s); s = fmaf(v0.y, v0.y, s);
    s = fmaf(v0.z, v0.z, s); s = fmaf(v0.w, v0.w, s);
    s = fmaf(v1.x, v1.x, s); s = fmaf(v1.y, v1.y, s);
    s = fmaf(v1.z, v1.z, s); s = fmaf(v1.w, v1.w, s);
    return s;
}

// Order-preserving float->u32 (monotone for ALL floats incl. negatives)
__device__ inline unsigned fkey(float f) {
    unsigned u = __float_as_uint(f);
    return u ^ (((int)u < 0) ? 0xFFFFFFFFu : 0x80000000u);
}

// Kernel 0: pre-split feature into MFMA-A-fragment bf16 hi/lo; block 0 also
// re-inits the 512-entry atomic-min table (re-poison safe: runs every launch).
__global__ __launch_bounds__(512) void split_feature_init(
    const float* __restrict__ feature, s8* __restrict__ fH, s8* __restrict__ fL,
    unsigned long long* __restrict__ mins)
{
    const int t    = blockIdx.x * 512 + threadIdx.x;   // 0..8191
    if (blockIdx.x == 0) mins[threadIdx.x] = ~0ull;    // [0..255]=primary,[256..511]=fallback
    const int lane = t & 63, ks = (t >> 6) & 7, rt = t >> 9;
    const int row  = rt * 16 + (lane & 15);
    const int k0   = ks * 32 + (lane >> 4) * 8;
    const float* p = feature + (size_t)row * DDIM + k0;
    const float4 v0 = *(const float4*)p;
    const float4 v1 = *(const float4*)(p + 4);
    s8 h, l;
    split8(v0, v1, h, l);
    fH[t] = h; fL[t] = l;
}

// Kernel 1: R6's proven M-split half-K GEMM + masked argmin (97.4 us, VGPR 48,
// 0 bank conflicts), with three deltas:
//  (1) epilogue writes ONE atomicMin-u64 per (row,kind) instead of 6.4 MB of
//      partials -> reduce_gather kernel deleted (one less launch). Key =
//      (monotone float bits << 32) | index: tie = lower index = argmin-first.
//  (2) 3-MFMA split scheme: aL*bl dropped (contribution ~6e-5 on scores vs
//      expected min-gap ~0.04 -> P(argmin flip) ~0.2%).
//  (3) s_setprio(1) around MFMA clusters (blocks on a CU are phase-diverse).
__global__ __launch_bounds__(512, 4) void gemm_argmin_msplit(
    const s8* __restrict__ fH, const s8* __restrict__ fL,
    const float* __restrict__ bank,
    const int* __restrict__ cluster_label, const int* __restrict__ class_label,
    const int* __restrict__ cluster_idx,  const int* __restrict__ gt_label,
    unsigned long long* __restrict__ mins)
{
    __shared__ __align__(16) s8 bHs[4 * 4 * 64];   // [sl][ct][fraglane] 16 KB
    __shared__ __align__(16) s8 bLs[4 * 4 * 64];   // 16 KB
    __shared__ float b2s[BN];
    __shared__ int clsS[BN], cluS[BN], rowGt[128], rowClu[128];

    const int tid = threadIdx.x;
    const int bb  = blockIdx.x;
    const int jb  = bb >> 1, mh = bb & 1;          // bank tile, M-half
    const int j0  = jb * BN;
    const int r0  = mh * 128;

    // Staging role: col = tid>>3 (0..63), q = tid&7; per half: two 8-float octets
    const int col = tid >> 3, q = tid & 7;
    const int ct_s = col >> 4, cl_s = col & 15;
    const int sl_s = q >> 1, p_s = q & 1;          // slice-in-half, octet-pair
    // Compute/epilogue role: wave w (0..7) owns global row-tile mh*8 + w
    const int w = tid >> 6, lane = tid & 63;
    const int g = lane >> 4, c = lane & 15;

    int jcol = j0 + col; if (jcol >= NBANK) jcol = NBANK - 1;
    const float* gb = bank + (size_t)jcol * DDIM + q * 16;   // +128 for half 1

    // ---- Prologue: labels + half-0 loads (16 floats/thread)
    if (tid < 128) {
        rowGt[tid]  = gt_label[r0 + tid];
        rowClu[tid] = cluster_idx[r0 + tid];
    }
    if (tid < BN) {
        int jg = j0 + tid; int jc = jg < NBANK ? jg : NBANK - 1;
        clsS[tid] = class_label[jc];
        cluS[tid] = cluster_label[jc];
    }
    float4 a0 = *(const float4*)(gb);
    float4 a1 = *(const float4*)(gb + 4);
    float4 a2 = *(const float4*)(gb + 8);
    float4 a3 = *(const float4*)(gb + 12);

    // ---- Stage half 0 (slices 0..3). Writer XOR ^q (R6-verified: 0 conflicts).
    float sqa = 0.f;
    {
        s8 h, l;
        split8(a0, a1, h, l);
        sqa = sq8(a0, a1, sqa);
        int wi = (((sl_s * 4 + ct_s) * 64 + (p_s * 2 + 0) * 16 + cl_s)) ^ q;
        bHs[wi] = h; bLs[wi] = l;
        split8(a2, a3, h, l);
        sqa = sq8(a2, a3, sqa);
        wi = (((sl_s * 4 + ct_s) * 64 + (p_s * 2 + 1) * 16 + cl_s)) ^ q;
        bHs[wi] = h; bLs[wi] = l;
    }
    __syncthreads();                       // bar1: half-0 staged

    // ---- Issue half-1 loads NOW; land under compute-h0 (16 VGPRs held)
    a0 = *(const float4*)(gb + 128);
    a1 = *(const float4*)(gb + 132);
    a2 = *(const float4*)(gb + 136);
    a3 = *(const float4*)(gb + 140);

    f32x4 acc[4];
    #pragma unroll
    for (int ct = 0; ct < 4; ++ct)
        acc[ct] = (f32x4){0.f, 0.f, 0.f, 0.f};

    const int RT = mh * 8 + w;                     // this wave's global row-tile

    // ---- Compute half 0: global slices 0..3; 3 MFMAs per (sl,ct)
    __builtin_amdgcn_s_setprio(1);
    #pragma unroll
    for (int sl = 0; sl < 4; ++sl) {
        const s8 aH = fH[(RT * 8 + sl) * 64 + lane];
        const s8 aL = fL[(RT * 8 + sl) * 64 + lane];
        const int rx = sl * 2 + (lane >> 5);       // = writer's q for this slot
        #pragma unroll
        for (int ct = 0; ct < 4; ++ct) {
            const s8 bh = bHs[((sl * 4 + ct) * 64 + lane) ^ rx];
            const s8 bl = bLs[((sl * 4 + ct) * 64 + lane) ^ rx];
            acc[ct] = __builtin_amdgcn_mfma_f32_16x16x32_bf16(aH, bh, acc[ct], 0, 0, 0);
            acc[ct] = __builtin_amdgcn_mfma_f32_16x16x32_bf16(aH, bl, acc[ct], 0, 0, 0);
            acc[ct] = __builtin_amdgcn_mfma_f32_16x16x32_bf16(aL, bh, acc[ct], 0, 0, 0);
        }
    }
    __builtin_amdgcn_s_setprio(0);
    __syncthreads();                       // bar2: all reads of half-0 LDS done

    // ---- Stage half 1 (slices 4..7 overwrite the same buffers)
    {
        s8 h, l;
        split8(a0, a1, h, l);
        sqa = sq8(a0, a1, sqa);
        int wi = (((sl_s * 4 + ct_s) * 64 + (p_s * 2 + 0) * 16 + cl_s)) ^ q;
        bHs[wi] = h; bLs[wi] = l;
        split8(a2, a3, h, l);
        sqa = sq8(a2, a3, sqa);
        wi = (((sl_s * 4 + ct_s) * 64 + (p_s * 2 + 1) * 16 + cl_s)) ^ q;
        bHs[wi] = h; bLs[wi] = l;
    }
    // ||b||^2 over full K: 8 q-threads of each col are adjacent lanes
    sqa += __shfl_xor(sqa, 1);
    sqa += __shfl_xor(sqa, 2);
    sqa += __shfl_xor(sqa, 4);
    if (q == 0) b2s[col] = sqa;
    __syncthreads();                       // bar3: half-1 staged, b2s visible

    // ---- Compute half 1: global slices 4..7
    __builtin_amdgcn_s_setprio(1);
    #pragma unroll
    for (int sl = 0; sl < 4; ++sl) {
        const s8 aH = fH[(RT * 8 + 4 + sl) * 64 + lane];
        const s8 aL = fL[(RT * 8 + 4 + sl) * 64 + lane];
        const int rx = sl * 2 + (lane >> 5);
        #pragma unroll
        for (int ct = 0; ct < 4; ++ct) {
            const s8 bh = bHs[((sl * 4 + ct) * 64 + lane) ^ rx];
            const s8 bl = bLs[((sl * 4 + ct) * 64 + lane) ^ rx];
            acc[ct] = __builtin_amdgcn_mfma_f32_16x16x32_bf16(aH, bh, acc[ct], 0, 0, 0);
            acc[ct] = __builtin_amdgcn_mfma_f32_16x16x32_bf16(aH, bl, acc[ct], 0, 0, 0);
            acc[ct] = __builtin_amdgcn_mfma_f32_16x16x32_bf16(aL, bh, acc[ct], 0, 0, 0);
        }
    }
    __builtin_amdgcn_s_setprio(0);

    // ---- Epilogue: C/D layout col = lane&15, row = g*4 + reg (HW-verified)
    #pragma unroll
    for (int r = 0; r < 4; ++r) {
        const int lrow = w * 16 + g * 4 + r;       // 0..127 within this M-half
        const int myGt = rowGt[lrow], myClu = rowClu[lrow];
        float bpv = SENT, bdv = SENT;
        int   bpi = INT_MAX, bdi = INT_MAX;
        #pragma unroll
        for (int ct = 0; ct < 4; ++ct) {   // ascending ct = ascending col per lane
            const int jg = j0 + ct * 16 + c;
            const float sc = b2s[ct * 16 + c] - 2.f * acc[ct][r];
            if (jg < NBANK && clsS[ct * 16 + c] != myGt) {
                if (sc < bdv) { bdv = sc; bdi = jg; }
                if (cluS[ct * 16 + c] == myClu && sc < bpv) { bpv = sc; bpi = jg; }
            }
        }
        #pragma unroll
        for (int off = 1; off < 16; off <<= 1) {   // tie-aware 16-lane reduce
            float vv = __shfl_xor(bpv, off); int ii = __shfl_xor(bpi, off);
            if (vv < bpv || (vv == bpv && ii < bpi)) { bpv = vv; bpi = ii; }
            vv = __shfl_xor(bdv, off); ii = __shfl_xor(bdi, off);
            if (vv < bdv || (vv == bdv && ii < bdi)) { bdv = vv; bdi = ii; }
        }
        if (c == 0) {
            const int grow = r0 + lrow;            // global row 0..255
            if (bpv < SENT)
                atomicMin(&mins[grow],
                          ((unsigned long long)fkey(bpv) << 32) | (unsigned)bpi);
            if (bdv < SENT)
                atomicMin(&mins[256 + grow],
                          ((unsigned long long)fkey(bdv) << 32) | (unsigned)bdi);
        }
    }
}

// Kernel 2: trivial gather — pick primary if any, else fallback, else 0.
__global__ __launch_bounds__(256) void gather_out(
    const unsigned long long* __restrict__ mins,
    const float* __restrict__ bank, float* __restrict__ out)
{
    const int row = blockIdx.x, tid = threadIdx.x;
    __shared__ int sIdx;
    if (tid == 0) {
        unsigned long long p = mins[row], d = mins[256 + row];
        int idx = 0;
        if (p != ~0ull)      idx = (int)(p & 0xFFFFFFFFull);
        else if (d != ~0ull) idx = (int)(d & 0xFFFFFFFFull);
        sIdx = idx;
    }
    __syncthreads();
    out[(size_t)row * DDIM + tid] = bank[(size_t)sIdx * DDIM + tid];
}

extern "C" void kernel_launch(void* const* d_in, const int* in_sizes, int n_in,
                              void* d_out, int out_size, void* d_ws, size_t ws_size,
                              hipStream_t stream) {
    const float* feature       = (const float*)d_in[0];
    const float* bank          = (const float*)d_in[1];
    const int*   cluster_label = (const int*)d_in[2];
    const int*   class_label   = (const int*)d_in[3];
    const int*   cluster_idx   = (const int*)d_in[4];
    const int*   gt_label      = (const int*)d_in[5];
    float* out = (float*)d_out;

    // Workspace: fH/fL (128 KB each) + mins table (4 KB)
    s8* fH = (s8*)d_ws;                 // 8192 frags
    s8* fL = fH + 8192;
    unsigned long long* mins = (unsigned long long*)((char*)d_ws + 2 * 8192 * sizeof(s8));

    hipLaunchKernelGGL(split_feature_init, dim3(16), dim3(512), 0, stream,
                       feature, fH, fL, mins);
    hipLaunchKernelGGL(gemm_argmin_msplit, dim3(NJB * 2), dim3(512), 0, stream,
                       fH, fL, bank, cluster_label, class_label, cluster_idx, gt_label,
                       mins);
    hipLaunchKernelGGL(gather_out, dim3(BQ), dim3(256), 0, stream,
                       mins, bank, out);
}

// Round 9
// 217.788 us; speedup vs baseline: 1.2499x; 1.2499x over previous
//
#include <hip/hip_runtime.h>
#include <climits>

typedef __attribute__((ext_vector_type(8))) short s8;      // 8 bf16 = 4 VGPRs
typedef __attribute__((ext_vector_type(4))) float f32x4;   // MFMA acc

#define BQ    256
#define DDIM  256
#define NBANK 100000
#define BN    64                          // bank cols per tile (4 col-tiles of 16)
#define NJB   ((NBANK + BN - 1) / BN)     // 1563
#define SENT  1e30f

// Split fp32 x into bf16 hi (round-half-up) + bf16 lo: x ~= hi + lo, |err| <~ 2^-18|x|
__device__ inline void splitElem(float x, s8& h, s8& l, int i) {
    unsigned u  = __float_as_uint(x);
    unsigned uh = (u + 0x8000u) & 0xFFFF0000u;
    h[i] = (short)(uh >> 16);
    float lf = x - __uint_as_float(uh);            // exact
    l[i] = (short)((__float_as_uint(lf) + 0x8000u) >> 16);
}

__device__ inline void split8(const float4 v0, const float4 v1, s8& h, s8& l) {
    splitElem(v0.x, h, l, 0); splitElem(v0.y, h, l, 1);
    splitElem(v0.z, h, l, 2); splitElem(v0.w, h, l, 3);
    splitElem(v1.x, h, l, 4); splitElem(v1.y, h, l, 5);
    splitElem(v1.z, h, l, 6); splitElem(v1.w, h, l, 7);
}

__device__ inline float sq8(const float4 v0, const float4 v1, float s) {
    s = fmaf(v0.x, v0.x, s); s = fmaf(v0.y, v0.y, s);
    s = fmaf(v0.z, v0.z, s); s = fmaf(v0.w, v0.w, s);
    s = fmaf(v1.x, v1.x, s); s = fmaf(v1.y, v1.y, s);
    s = fmaf(v1.z, v1.z, s); s = fmaf(v1.w, v1.w, s);
    return s;
}

// Order-preserving float->u32 (monotone for ALL floats incl. negatives)
__device__ inline unsigned fkey(float f) {
    unsigned u = __float_as_uint(f);
    return u ^ (((int)u < 0) ? 0xFFFFFFFFu : 0x80000000u);
}

// Kernel 0: pre-split the tiny A (feature) into MFMA-A-fragment-ordered bf16 hi/lo.
__global__ __launch_bounds__(512) void split_feature(
    const float* __restrict__ feature, s8* __restrict__ fH, s8* __restrict__ fL)
{
    const int t    = blockIdx.x * 512 + threadIdx.x;   // 0..8191
    const int lane = t & 63, ks = (t >> 6) & 7, rt = t >> 9;
    const int row  = rt * 16 + (lane & 15);
    const int k0   = ks * 32 + (lane >> 4) * 8;
    const float* p = feature + (size_t)row * DDIM + k0;
    const float4 v0 = *(const float4*)p;
    const float4 v1 = *(const float4*)(p + 4);
    s8 h, l;
    split8(v0, v1, h, l);
    fH[t] = h; fL[t] = l;
}

// Kernel 1: R6's proven M-split half-K GEMM (97.4 us, VGPR 48, 0 conflicts)
// with exactly TWO hardware-validated deltas from R8 (whose atomics are REMOVED
// — 800k device-scope atomicMin to a 4 KB table cost +57 us):
//  (1) 3-MFMA split scheme (aH*bh + aH*bl + aL*bh; aL*bl dropped): -25% matrix
//      work, verified absmax 0.0 on HW in R8.
//  (2) u64 min-keys (fkey(val)<<32 | idx): single-compare, tie-exact
//      (equal value -> lower index = argmin-first). Streamed to partial
//      arrays like R6, NOT atomics.
__global__ __launch_bounds__(512, 4) void gemm_argmin_msplit(
    const s8* __restrict__ fH, const s8* __restrict__ fL,
    const float* __restrict__ bank,
    const int* __restrict__ cluster_label, const int* __restrict__ class_label,
    const int* __restrict__ cluster_idx,  const int* __restrict__ gt_label,
    unsigned long long* __restrict__ wsP, unsigned long long* __restrict__ wsD)
{
    __shared__ __align__(16) s8 bHs[4 * 4 * 64];   // [sl][ct][fraglane] 16 KB
    __shared__ __align__(16) s8 bLs[4 * 4 * 64];   // 16 KB
    __shared__ float b2s[BN];
    __shared__ int clsS[BN], cluS[BN], rowGt[128], rowClu[128];

    const int tid = threadIdx.x;
    const int bb  = blockIdx.x;
    const int jb  = bb >> 1, mh = bb & 1;          // bank tile, M-half
    const int j0  = jb * BN;
    const int r0  = mh * 128;

    // Staging role: col = tid>>3 (0..63), q = tid&7; per half: two 8-float octets
    const int col = tid >> 3, q = tid & 7;
    const int ct_s = col >> 4, cl_s = col & 15;
    const int sl_s = q >> 1, p_s = q & 1;          // slice-in-half, octet-pair
    // Compute/epilogue role: wave w (0..7) owns global row-tile mh*8 + w
    const int w = tid >> 6, lane = tid & 63;
    const int g = lane >> 4, c = lane & 15;

    int jcol = j0 + col; if (jcol >= NBANK) jcol = NBANK - 1;
    const float* gb = bank + (size_t)jcol * DDIM + q * 16;   // +128 for half 1

    // ---- Prologue: labels + half-0 loads (16 floats/thread)
    if (tid < 128) {
        rowGt[tid]  = gt_label[r0 + tid];
        rowClu[tid] = cluster_idx[r0 + tid];
    }
    if (tid < BN) {
        int jg = j0 + tid; int jc = jg < NBANK ? jg : NBANK - 1;
        clsS[tid] = class_label[jc];
        cluS[tid] = cluster_label[jc];
    }
    float4 a0 = *(const float4*)(gb);
    float4 a1 = *(const float4*)(gb + 4);
    float4 a2 = *(const float4*)(gb + 8);
    float4 a3 = *(const float4*)(gb + 12);

    // ---- Stage half 0 (slices 0..3). Writer XOR ^q (R6-verified: 0 conflicts).
    float sqa = 0.f;
    {
        s8 h, l;
        split8(a0, a1, h, l);
        sqa = sq8(a0, a1, sqa);
        int wi = (((sl_s * 4 + ct_s) * 64 + (p_s * 2 + 0) * 16 + cl_s)) ^ q;
        bHs[wi] = h; bLs[wi] = l;
        split8(a2, a3, h, l);
        sqa = sq8(a2, a3, sqa);
        wi = (((sl_s * 4 + ct_s) * 64 + (p_s * 2 + 1) * 16 + cl_s)) ^ q;
        bHs[wi] = h; bLs[wi] = l;
    }
    __syncthreads();                       // bar1: half-0 staged

    // ---- Issue half-1 loads NOW; land under compute-h0 (16 VGPRs held)
    a0 = *(const float4*)(gb + 128);
    a1 = *(const float4*)(gb + 132);
    a2 = *(const float4*)(gb + 136);
    a3 = *(const float4*)(gb + 140);

    f32x4 acc[4];
    #pragma unroll
    for (int ct = 0; ct < 4; ++ct)
        acc[ct] = (f32x4){0.f, 0.f, 0.f, 0.f};

    const int RT = mh * 8 + w;                     // this wave's global row-tile

    // ---- Compute half 0: global slices 0..3; 3 MFMAs per (sl,ct)
    #pragma unroll
    for (int sl = 0; sl < 4; ++sl) {
        const s8 aH = fH[(RT * 8 + sl) * 64 + lane];
        const s8 aL = fL[(RT * 8 + sl) * 64 + lane];
        const int rx = sl * 2 + (lane >> 5);       // = writer's q for this slot
        #pragma unroll
        for (int ct = 0; ct < 4; ++ct) {
            const s8 bh = bHs[((sl * 4 + ct) * 64 + lane) ^ rx];
            const s8 bl = bLs[((sl * 4 + ct) * 64 + lane) ^ rx];
            acc[ct] = __builtin_amdgcn_mfma_f32_16x16x32_bf16(aH, bh, acc[ct], 0, 0, 0);
            acc[ct] = __builtin_amdgcn_mfma_f32_16x16x32_bf16(aH, bl, acc[ct], 0, 0, 0);
            acc[ct] = __builtin_amdgcn_mfma_f32_16x16x32_bf16(aL, bh, acc[ct], 0, 0, 0);
        }
    }
    __syncthreads();                       // bar2: all reads of half-0 LDS done

    // ---- Stage half 1 (slices 4..7 overwrite the same buffers)
    {
        s8 h, l;
        split8(a0, a1, h, l);
        sqa = sq8(a0, a1, sqa);
        int wi = (((sl_s * 4 + ct_s) * 64 + (p_s * 2 + 0) * 16 + cl_s)) ^ q;
        bHs[wi] = h; bLs[wi] = l;
        split8(a2, a3, h, l);
        sqa = sq8(a2, a3, sqa);
        wi = (((sl_s * 4 + ct_s) * 64 + (p_s * 2 + 1) * 16 + cl_s)) ^ q;
        bHs[wi] = h; bLs[wi] = l;
    }
    // ||b||^2 over full K: 8 q-threads of each col are adjacent lanes
    sqa += __shfl_xor(sqa, 1);
    sqa += __shfl_xor(sqa, 2);
    sqa += __shfl_xor(sqa, 4);
    if (q == 0) b2s[col] = sqa;
    __syncthreads();                       // bar3: half-1 staged, b2s visible

    // ---- Compute half 1: global slices 4..7
    #pragma unroll
    for (int sl = 0; sl < 4; ++sl) {
        const s8 aH = fH[(RT * 8 + 4 + sl) * 64 + lane];
        const s8 aL = fL[(RT * 8 + 4 + sl) * 64 + lane];
        const int rx = sl * 2 + (lane >> 5);
        #pragma unroll
        for (int ct = 0; ct < 4; ++ct) {
            const s8 bh = bHs[((sl * 4 + ct) * 64 + lane) ^ rx];
            const s8 bl = bLs[((sl * 4 + ct) * 64 + lane) ^ rx];
            acc[ct] = __builtin_amdgcn_mfma_f32_16x16x32_bf16(aH, bh, acc[ct], 0, 0, 0);
            acc[ct] = __builtin_amdgcn_mfma_f32_16x16x32_bf16(aH, bl, acc[ct], 0, 0, 0);
            acc[ct] = __builtin_amdgcn_mfma_f32_16x16x32_bf16(aL, bh, acc[ct], 0, 0, 0);
        }
    }

    // ---- Epilogue: C/D layout col = lane&15, row = g*4 + reg (HW-verified).
    // u64 keys: min over candidates, tie -> lower index automatically.
    #pragma unroll
    for (int r = 0; r < 4; ++r) {
        const int lrow = w * 16 + g * 4 + r;       // 0..127 within this M-half
        const int myGt = rowGt[lrow], myClu = rowClu[lrow];
        unsigned long long pk = ~0ull, dk = ~0ull;
        #pragma unroll
        for (int ct = 0; ct < 4; ++ct) {
            const int jg = j0 + ct * 16 + c;
            const float sc = b2s[ct * 16 + c] - 2.f * acc[ct][r];
            if (jg < NBANK && clsS[ct * 16 + c] != myGt) {
                const unsigned long long k =
                    ((unsigned long long)fkey(sc) << 32) | (unsigned)jg;
                dk = k < dk ? k : dk;
                if (cluS[ct * 16 + c] == myClu) pk = k < pk ? k : pk;
            }
        }
        #pragma unroll
        for (int off = 1; off < 16; off <<= 1) {   // 16-lane u64 min-reduce
            unsigned long long ok = __shfl_xor(pk, off);
            pk = ok < pk ? ok : pk;
            ok = __shfl_xor(dk, off);
            dk = ok < dk ? ok : dk;
        }
        if (c == 0) {
            const size_t o = (size_t)jb * BQ + r0 + lrow;  // [jb][row]: 2KB runs
            wsP[o] = pk;
            wsD[o] = dk;
        }
    }
}

// Kernel 2: per-row u64-min over NJB partials, fallback select, gather bank row.
__global__ __launch_bounds__(256) void reduce_gather(
    const unsigned long long* __restrict__ wsP,
    const unsigned long long* __restrict__ wsD,
    const float* __restrict__ bank, float* __restrict__ out)
{
    const int row = blockIdx.x, tid = threadIdx.x;
    unsigned long long pk = ~0ull, dk = ~0ull;
    for (int b = tid; b < NJB; b += 256) {
        unsigned long long k = wsP[(size_t)b * BQ + row];
        pk = k < pk ? k : pk;
        k = wsD[(size_t)b * BQ + row];
        dk = k < dk ? k : dk;
    }
    #pragma unroll
    for (int off = 32; off > 0; off >>= 1) {
        unsigned long long ok = __shfl_down(pk, off);
        pk = ok < pk ? ok : pk;
        ok = __shfl_down(dk, off);
        dk = ok < dk ? ok : dk;
    }
    __shared__ unsigned long long swP[4], swD[4];
    __shared__ int sIdx;
    const int lane = tid & 63, wv = tid >> 6;
    if (lane == 0) { swP[wv] = pk; swD[wv] = dk; }
    __syncthreads();
    if (tid == 0) {
        unsigned long long p = swP[0], d = swD[0];
        #pragma unroll
        for (int k2 = 1; k2 < 4; ++k2) {
            p = swP[k2] < p ? swP[k2] : p;
            d = swD[k2] < d ? swD[k2] : d;
        }
        sIdx = (p != ~0ull) ? (int)(unsigned)(p & 0xFFFFFFFFull)
             : ((d != ~0ull) ? (int)(unsigned)(d & 0xFFFFFFFFull) : 0);
    }
    __syncthreads();
    out[(size_t)row * DDIM + tid] = bank[(size_t)sIdx * DDIM + tid];
}

extern "C" void kernel_launch(void* const* d_in, const int* in_sizes, int n_in,
                              void* d_out, int out_size, void* d_ws, size_t ws_size,
                              hipStream_t stream) {
    const float* feature       = (const float*)d_in[0];
    const float* bank          = (const float*)d_in[1];
    const int*   cluster_label = (const int*)d_in[2];
    const int*   class_label   = (const int*)d_in[3];
    const int*   cluster_idx   = (const int*)d_in[4];
    const int*   gt_label      = (const int*)d_in[5];
    float* out = (float*)d_out;

    // Workspace: fH/fL (128 KB each) + 2 u64 key arrays [NJB][256] (3.2 MB each)
    s8* fH = (s8*)d_ws;                 // 8192 frags
    s8* fL = fH + 8192;
    unsigned long long* wsP = (unsigned long long*)((char*)d_ws + 2 * 8192 * sizeof(s8));
    unsigned long long* wsD = wsP + (size_t)BQ * NJB;

    hipLaunchKernelGGL(split_feature, dim3(16), dim3(512), 0, stream, feature, fH, fL);
    hipLaunchKernelGGL(gemm_argmin_msplit, dim3(NJB * 2), dim3(512), 0, stream,
                       fH, fL, bank, cluster_label, class_label, cluster_idx, gt_label,
                       wsP, wsD);
    hipLaunchKernelGGL(reduce_gather, dim3(BQ), dim3(256), 0, stream,
                       wsP, wsD, bank, out);
}

// Round 10
// 214.857 us; speedup vs baseline: 1.2669x; 1.0136x over previous
//
#include <hip/hip_runtime.h>
#include <climits>

typedef __attribute__((ext_vector_type(8))) short s8;      // 8 bf16 = 4 VGPRs
typedef __attribute__((ext_vector_type(4))) float f32x4;   // MFMA acc

#define BQ    256
#define DDIM  256
#define NBANK 100000
#define BN    64                          // bank cols per LDS pass
#define NJB   ((NBANK + BN - 1) / BN)     // 1563 64-col tiles
#define NJB2  ((NJB + 1) / 2)             // 782 128-col groups
#define SENT  1e30f

// Split fp32 x into bf16 hi (round-half-up) + bf16 lo: x ~= hi + lo
__device__ inline void splitElem(float x, s8& h, s8& l, int i) {
    unsigned u  = __float_as_uint(x);
    unsigned uh = (u + 0x8000u) & 0xFFFF0000u;
    h[i] = (short)(uh >> 16);
    float lf = x - __uint_as_float(uh);            // exact
    l[i] = (short)((__float_as_uint(lf) + 0x8000u) >> 16);
}

__device__ inline void split8(const float4 v0, const float4 v1, s8& h, s8& l) {
    splitElem(v0.x, h, l, 0); splitElem(v0.y, h, l, 1);
    splitElem(v0.z, h, l, 2); splitElem(v0.w, h, l, 3);
    splitElem(v1.x, h, l, 4); splitElem(v1.y, h, l, 5);
    splitElem(v1.z, h, l, 6); splitElem(v1.w, h, l, 7);
}

__device__ inline float sq8(const float4 v0, const float4 v1, float s) {
    s = fmaf(v0.x, v0.x, s); s = fmaf(v0.y, v0.y, s);
    s = fmaf(v0.z, v0.z, s); s = fmaf(v0.w, v0.w, s);
    s = fmaf(v1.x, v1.x, s); s = fmaf(v1.y, v1.y, s);
    s = fmaf(v1.z, v1.z, s); s = fmaf(v1.w, v1.w, s);
    return s;
}

// Order-preserving float->u32 (monotone for ALL floats incl. negatives)
__device__ inline unsigned fkey(float f) {
    unsigned u = __float_as_uint(f);
    return u ^ (((int)u < 0) ? 0xFFFFFFFFu : 0x80000000u);
}

// Kernel 0: pre-split the tiny A (feature) into MFMA-A-fragment-ordered bf16 hi/lo.
__global__ __launch_bounds__(512) void split_feature(
    const float* __restrict__ feature, s8* __restrict__ fH, s8* __restrict__ fL)
{
    const int t    = blockIdx.x * 512 + threadIdx.x;   // 0..8191
    const int lane = t & 63, ks = (t >> 6) & 7, rt = t >> 9;
    const int row  = rt * 16 + (lane & 15);
    const int k0   = ks * 32 + (lane >> 4) * 8;
    const float* p = feature + (size_t)row * DDIM + k0;
    const float4 v0 = *(const float4*)p;
    const float4 v1 = *(const float4*)(p + 4);
    s8 h, l;
    split8(v0, v1, h, l);
    fH[t] = h; fL[t] = l;
}

// Kernel 1: TWO-TILE M-split half-K GEMM + fused masked argmin.
// R9 (90.1 us, VGPR 48, 0 conflicts) + one structural change: each block covers
// a 128-col group as two sequential 64-col LDS passes. Effects: (a) 1564 blocks
// instead of 3126 -> half the cold staging starts; every half-stage's loads
// except the first are issued a full compute phase ahead; (b) pass-0 epilogue
// STASHES per-lane keys in regs (no shuffle) and only pass-1 does the merged
// 16-lane u64 shuffle-reduce -> half the ds-bpermute chains (~2-3k cy/wave
// each, comparable to the whole MFMA phase); (c) ws halves to 3.4 MB.
// 3-MFMA split scheme (absmax-0-validated R8/R9) + u64 tie-exact keys kept.
__global__ __launch_bounds__(512, 4) void gemm_argmin_2t(
    const s8* __restrict__ fH, const s8* __restrict__ fL,
    const float* __restrict__ bank,
    const int* __restrict__ cluster_label, const int* __restrict__ class_label,
    const int* __restrict__ cluster_idx,  const int* __restrict__ gt_label,
    unsigned long long* __restrict__ wsP, unsigned long long* __restrict__ wsD)
{
    __shared__ __align__(16) s8 bHs[4 * 4 * 64];   // [sl][ct][fraglane] 16 KB
    __shared__ __align__(16) s8 bLs[4 * 4 * 64];   // 16 KB
    __shared__ float b2s[128];                     // ||b||^2, both passes
    __shared__ int clsS[128], cluS[128], rowGt[128], rowClu[128];

    const int tid = threadIdx.x;
    const int bb  = blockIdx.x;
    const int jb2 = bb >> 1, mh = bb & 1;          // 128-col group, M-half
    const int j0  = jb2 * 128;
    const int r0  = mh * 128;

    // Staging role: col = tid>>3 (0..63), q = tid&7; per half: two 8-float octets
    const int col = tid >> 3, q = tid & 7;
    const int ct_s = col >> 4, cl_s = col & 15;
    const int sl_s = q >> 1, p_s = q & 1;          // slice-in-half, octet-pair
    // Compute/epilogue role: wave w (0..7) owns global row-tile mh*8 + w
    const int w = tid >> 6, lane = tid & 63;
    const int g = lane >> 4, c = lane & 15;
    const int RT = mh * 8 + w;

    int jc0 = j0 + col;      if (jc0 >= NBANK) jc0 = NBANK - 1;
    int jc1 = j0 + 64 + col; if (jc1 >= NBANK) jc1 = NBANK - 1;
    const float* gb0 = bank + (size_t)jc0 * DDIM + q * 16;   // pass 0 (+128 = h1)
    const float* gb1 = bank + (size_t)jc1 * DDIM + q * 16;   // pass 1

    // ---- Prologue: labels (128 rows of this M-half; 128 cols of this group)
    if (tid < 128) {
        rowGt[tid]  = gt_label[r0 + tid];
        rowClu[tid] = cluster_idx[r0 + tid];
        int jg = j0 + tid; int jc = jg < NBANK ? jg : NBANK - 1;
        clsS[tid] = class_label[jc];
        cluS[tid] = cluster_label[jc];
    }
    float4 a0 = *(const float4*)(gb0);
    float4 a1 = *(const float4*)(gb0 + 4);
    float4 a2 = *(const float4*)(gb0 + 8);
    float4 a3 = *(const float4*)(gb0 + 12);

#define STAGE(SQA)                                                             \
    {                                                                          \
        s8 h_, l_;                                                             \
        split8(a0, a1, h_, l_);                                                \
        SQA = sq8(a0, a1, SQA);                                                \
        int wi_ = (((sl_s * 4 + ct_s) * 64 + (p_s * 2 + 0) * 16 + cl_s)) ^ q;  \
        bHs[wi_] = h_; bLs[wi_] = l_;                                          \
        split8(a2, a3, h_, l_);                                                \
        SQA = sq8(a2, a3, SQA);                                                \
        wi_ = (((sl_s * 4 + ct_s) * 64 + (p_s * 2 + 1) * 16 + cl_s)) ^ q;      \
        bHs[wi_] = h_; bLs[wi_] = l_;                                          \
    }

#define LOADA(PTR, OFF)                                                        \
    a0 = *(const float4*)((PTR) + (OFF));                                      \
    a1 = *(const float4*)((PTR) + (OFF) + 4);                                  \
    a2 = *(const float4*)((PTR) + (OFF) + 8);                                  \
    a3 = *(const float4*)((PTR) + (OFF) + 12);

#define COMPUTE(HBASE)                                                         \
    _Pragma("unroll")                                                          \
    for (int sl = 0; sl < 4; ++sl) {                                           \
        const s8 aH = fH[(RT * 8 + (HBASE) + sl) * 64 + lane];                 \
        const s8 aL = fL[(RT * 8 + (HBASE) + sl) * 64 + lane];                 \
        const int rx = sl * 2 + (lane >> 5);                                   \
        _Pragma("unroll")                                                      \
        for (int ct = 0; ct < 4; ++ct) {                                       \
            const s8 bh = bHs[((sl * 4 + ct) * 64 + lane) ^ rx];               \
            const s8 bl = bLs[((sl * 4 + ct) * 64 + lane) ^ rx];               \
            acc[ct] = __builtin_amdgcn_mfma_f32_16x16x32_bf16(aH, bh, acc[ct], 0, 0, 0); \
            acc[ct] = __builtin_amdgcn_mfma_f32_16x16x32_bf16(aH, bl, acc[ct], 0, 0, 0); \
            acc[ct] = __builtin_amdgcn_mfma_f32_16x16x32_bf16(aL, bh, acc[ct], 0, 0, 0); \
        }                                                                      \
    }

    f32x4 acc[4];
    unsigned long long pkA[4], dkA[4];             // pass-0 stashed keys

    // ================= PASS 0 (cols j0 .. j0+63) =================
    float sqa = 0.f;
    STAGE(sqa);                            // h0p0
    __syncthreads();                       // bar1
    LOADA(gb0, 128);                       // h1p0 loads land under compute
    #pragma unroll
    for (int ct = 0; ct < 4; ++ct) acc[ct] = (f32x4){0.f, 0.f, 0.f, 0.f};
    COMPUTE(0);
    __syncthreads();                       // bar2
    STAGE(sqa);                            // h1p0
    sqa += __shfl_xor(sqa, 1);
    sqa += __shfl_xor(sqa, 2);
    sqa += __shfl_xor(sqa, 4);
    if (q == 0) b2s[col] = sqa;
    __syncthreads();                       // bar3
    LOADA(gb1, 0);                         // h0p1 loads land under compute
    COMPUTE(4);
    __syncthreads();                       // bar4: h1p0 LDS reads done

    // stage h0p1 + pass-0 epilogue (register stash only, no shuffles)
    sqa = 0.f;
    STAGE(sqa);                            // h0p1
    #pragma unroll
    for (int r = 0; r < 4; ++r) {
        const int lrow = w * 16 + g * 4 + r;
        const int myGt = rowGt[lrow], myClu = rowClu[lrow];
        unsigned long long pk = ~0ull, dk = ~0ull;
        #pragma unroll
        for (int ct = 0; ct < 4; ++ct) {
            const int li = ct * 16 + c;            // 0..63 (pass-0 labels/b2s)
            const int jg = j0 + li;
            const float sc = b2s[li] - 2.f * acc[ct][r];
            if (jg < NBANK && clsS[li] != myGt) {
                const unsigned long long k =
                    ((unsigned long long)fkey(sc) << 32) | (unsigned)jg;
                dk = k < dk ? k : dk;
                if (cluS[li] == myClu) pk = k < pk ? k : pk;
            }
        }
        pkA[r] = pk; dkA[r] = dk;
    }
    __syncthreads();                       // bar5

    // ================= PASS 1 (cols j0+64 .. j0+127) =================
    LOADA(gb1, 128);                       // h1p1 loads land under compute
    #pragma unroll
    for (int ct = 0; ct < 4; ++ct) acc[ct] = (f32x4){0.f, 0.f, 0.f, 0.f};
    COMPUTE(0);
    __syncthreads();                       // bar6
    STAGE(sqa);                            // h1p1
    sqa += __shfl_xor(sqa, 1);
    sqa += __shfl_xor(sqa, 2);
    sqa += __shfl_xor(sqa, 4);
    if (q == 0) b2s[64 + col] = sqa;
    __syncthreads();                       // bar7
    COMPUTE(4);

    // ---- Final epilogue: pass-1 keys, merge with stash, ONE 16-lane reduce
    #pragma unroll
    for (int r = 0; r < 4; ++r) {
        const int lrow = w * 16 + g * 4 + r;
        const int myGt = rowGt[lrow], myClu = rowClu[lrow];
        unsigned long long pk = pkA[r], dk = dkA[r];
        #pragma unroll
        for (int ct = 0; ct < 4; ++ct) {
            const int li = 64 + ct * 16 + c;       // pass-1 labels/b2s
            const int jg = j0 + li;
            const float sc = b2s[li] - 2.f * acc[ct][r];
            if (jg < NBANK && clsS[li] != myGt) {
                const unsigned long long k =
                    ((unsigned long long)fkey(sc) << 32) | (unsigned)jg;
                dk = k < dk ? k : dk;
                if (cluS[li] == myClu) pk = k < pk ? k : pk;
            }
        }
        #pragma unroll
        for (int off = 1; off < 16; off <<= 1) {   // 16-lane u64 min-reduce
            unsigned long long ok = __shfl_xor(pk, off);
            pk = ok < pk ? ok : pk;
            ok = __shfl_xor(dk, off);
            dk = ok < dk ? ok : dk;
        }
        if (c == 0) {
            const size_t o = (size_t)jb2 * BQ + r0 + lrow;  // [jb2][row]
            wsP[o] = pk;
            wsD[o] = dk;
        }
    }
#undef STAGE
#undef LOADA
#undef COMPUTE
}

// Kernel 2: per-row u64-min over NJB2 partials, fallback select, gather bank row.
__global__ __launch_bounds__(256) void reduce_gather(
    const unsigned long long* __restrict__ wsP,
    const unsigned long long* __restrict__ wsD,
    const float* __restrict__ bank, float* __restrict__ out)
{
    const int row = blockIdx.x, tid = threadIdx.x;
    unsigned long long pk = ~0ull, dk = ~0ull;
    for (int b = tid; b < NJB2; b += 256) {
        unsigned long long k = wsP[(size_t)b * BQ + row];
        pk = k < pk ? k : pk;
        k = wsD[(size_t)b * BQ + row];
        dk = k < dk ? k : dk;
    }
    #pragma unroll
    for (int off = 32; off > 0; off >>= 1) {
        unsigned long long ok = __shfl_down(pk, off);
        pk = ok < pk ? ok : pk;
        ok = __shfl_down(dk, off);
        dk = ok < dk ? ok : dk;
    }
    __shared__ unsigned long long swP[4], swD[4];
    __shared__ int sIdx;
    const int lane = tid & 63, wv = tid >> 6;
    if (lane == 0) { swP[wv] = pk; swD[wv] = dk; }
    __syncthreads();
    if (tid == 0) {
        unsigned long long p = swP[0], d = swD[0];
        #pragma unroll
        for (int k2 = 1; k2 < 4; ++k2) {
            p = swP[k2] < p ? swP[k2] : p;
            d = swD[k2] < d ? swD[k2] : d;
        }
        sIdx = (p != ~0ull) ? (int)(unsigned)(p & 0xFFFFFFFFull)
             : ((d != ~0ull) ? (int)(unsigned)(d & 0xFFFFFFFFull) : 0);
    }
    __syncthreads();
    out[(size_t)row * DDIM + tid] = bank[(size_t)sIdx * DDIM + tid];
}

extern "C" void kernel_launch(void* const* d_in, const int* in_sizes, int n_in,
                              void* d_out, int out_size, void* d_ws, size_t ws_size,
                              hipStream_t stream) {
    const float* feature       = (const float*)d_in[0];
    const float* bank          = (const float*)d_in[1];
    const int*   cluster_label = (const int*)d_in[2];
    const int*   class_label   = (const int*)d_in[3];
    const int*   cluster_idx   = (const int*)d_in[4];
    const int*   gt_label      = (const int*)d_in[5];
    float* out = (float*)d_out;

    // Workspace: fH/fL (128 KB each) + 2 u64 key arrays [NJB2][256] (1.6 MB each)
    s8* fH = (s8*)d_ws;                 // 8192 frags
    s8* fL = fH + 8192;
    unsigned long long* wsP = (unsigned long long*)((char*)d_ws + 2 * 8192 * sizeof(s8));
    unsigned long long* wsD = wsP + (size_t)BQ * NJB2;

    hipLaunchKernelGGL(split_feature, dim3(16), dim3(512), 0, stream, feature, fH, fL);
    hipLaunchKernelGGL(gemm_argmin_2t, dim3(NJB2 * 2), dim3(512), 0, stream,
                       fH, fL, bank, cluster_label, class_label, cluster_idx, gt_label,
                       wsP, wsD);
    hipLaunchKernelGGL(reduce_gather, dim3(BQ), dim3(256), 0, stream,
                       wsP, wsD, bank, out);
}